// Round 9
// baseline (1041.180 us; speedup 1.0000x reference)
//
#include <hip/hip_runtime.h>

#define D_MODEL 1024
#define D_FF    4096
#define N_EXP   8
#define BM 128
#define BN 128
#define BK 64

typedef __attribute__((ext_vector_type(8))) short bf16x8;
typedef __attribute__((ext_vector_type(4))) float f32x4;
typedef unsigned int u32;

__device__ __forceinline__ unsigned short f2bf(float f) {
  union { float f; unsigned u; } v; v.f = f;
  unsigned r = v.u + 0x7FFFu + ((v.u >> 16) & 1u);
  return (unsigned short)(r >> 16);
}

__device__ __forceinline__ void gl_lds16(const void* g, void* l) {
  __builtin_amdgcn_global_load_lds((const __attribute__((address_space(1))) u32*)g,
                                   (__attribute__((address_space(3))) u32*)l, 16, 0, 0);
}

// ---------------- transpose + convert W -> bf16 [e][n][k] ----------------
__global__ __launch_bounds__(256)
void transpose_convert_kernel(const float* __restrict__ src, unsigned short* __restrict__ dst,
                              int Ksub, int Nsrc, int k0, int n0, int Nchunk,
                              unsigned long long eStride) {
  __shared__ u32 s32k[32][65];  // [k/2][n]
  int e = blockIdx.z;
  int kb = blockIdx.x * 64, nb = blockIdx.y * 64;
  const float* se = src + (size_t)e * eStride + (size_t)(k0 + kb) * Nsrc + (n0 + nb);
  unsigned short* de = dst + (size_t)e * Nchunk * Ksub + (size_t)nb * Ksub + kb;
  int tid = threadIdx.x;
  int kh = tid >> 4;
  int n4 = (tid & 15) * 4;
  #pragma unroll
  for (int p = 0; p < 2; p++) {
    int k = kh * 2 + p * 32;
    float4 v0 = *(const float4*)(se + (size_t)k * Nsrc + n4);
    float4 v1 = *(const float4*)(se + (size_t)(k + 1) * Nsrc + n4);
    #pragma unroll
    for (int j = 0; j < 4; j++) {
      u32 pk = (u32)f2bf(((const float*)&v0)[j]) |
               ((u32)f2bf(((const float*)&v1)[j]) << 16);
      s32k[k >> 1][n4 + j] = pk;
    }
  }
  __syncthreads();
  #pragma unroll
  for (int c = 0; c < 2; c++) {
    int id = tid + c * 256;
    int n = id >> 3, kc = id & 7;
    uint4 o;
    o.x = s32k[kc * 4 + 0][n];
    o.y = s32k[kc * 4 + 1][n];
    o.z = s32k[kc * 4 + 2][n];
    o.w = s32k[kc * 4 + 3][n];
    *(uint4*)(de + (size_t)n * Ksub + kc * 8) = o;
  }
}

// ---------------- gating (+ fused x->bf16 convert): 1 wave per token ----------------
__global__ void gating_kernel(const float* __restrict__ x,
                              const float* __restrict__ Wg,
                              const float* __restrict__ bg,
                              float* __restrict__ gate_out,
                              unsigned short* __restrict__ xb,
                              int* __restrict__ cnt,
                              int* __restrict__ tokIdx,
                              float* __restrict__ tokW, int T) {
  int wv = threadIdx.x >> 6, lane = threadIdx.x & 63;
  int t = blockIdx.x * 4 + wv;
  if (t >= T) return;
  const float* xr = x + (size_t)t * D_MODEL + lane * 16;
  float acc[N_EXP];
  #pragma unroll
  for (int e = 0; e < N_EXP; e++) acc[e] = 0.f;
  ushort4 xc[4];
  #pragma unroll
  for (int q = 0; q < 4; q++) {
    float4 xv = *(const float4*)(xr + q * 4);
    xc[q].x = f2bf(xv.x); xc[q].y = f2bf(xv.y);
    xc[q].z = f2bf(xv.z); xc[q].w = f2bf(xv.w);
    #pragma unroll
    for (int r = 0; r < 4; r++) {
      float xs = ((const float*)&xv)[r];
      const float* wrow = Wg + (size_t)(lane * 16 + q * 4 + r) * N_EXP;
      float4 wa = *(const float4*)wrow;
      float4 wb = *(const float4*)(wrow + 4);
      acc[0] += xs * wa.x; acc[1] += xs * wa.y; acc[2] += xs * wa.z; acc[3] += xs * wa.w;
      acc[4] += xs * wb.x; acc[5] += xs * wb.y; acc[6] += xs * wb.z; acc[7] += xs * wb.w;
    }
  }
  unsigned short* xbr = xb + (size_t)t * D_MODEL + lane * 16;
  #pragma unroll
  for (int q = 0; q < 4; q++) *(ushort4*)(xbr + q * 4) = xc[q];
  #pragma unroll
  for (int off = 32; off > 0; off >>= 1) {
    #pragma unroll
    for (int e = 0; e < N_EXP; e++) acc[e] += __shfl_xor(acc[e], off);
  }
  if (lane == 0) {
    float l[N_EXP], p[N_EXP];
    float m = -1e30f;
    #pragma unroll
    for (int e = 0; e < N_EXP; e++) { l[e] = acc[e] + bg[e]; m = fmaxf(m, l[e]); }
    float s = 0.f;
    #pragma unroll
    for (int e = 0; e < N_EXP; e++) { p[e] = __expf(l[e] - m); s += p[e]; }
    float inv = 1.f / s;
    #pragma unroll
    for (int e = 0; e < N_EXP; e++) { p[e] *= inv; gate_out[(size_t)t * N_EXP + e] = p[e]; }
    int e1 = 0;
    #pragma unroll
    for (int e = 1; e < N_EXP; e++) if (p[e] > p[e1]) e1 = e;
    int e2 = (e1 == 0) ? 1 : 0;
    #pragma unroll
    for (int e = 0; e < N_EXP; e++) if (e != e1 && p[e] > p[e2]) e2 = e;
    int pos = atomicAdd(cnt + e1, 1);
    tokIdx[(size_t)e1 * T + pos] = t; tokW[(size_t)e1 * T + pos] = p[e1];
    pos = atomicAdd(cnt + e2, 1);
    tokIdx[(size_t)e2 * T + pos] = t; tokW[(size_t)e2 * T + pos] = p[e2];
  }
}

// ---------------- schedule: build row-tile table ----------------
__global__ void schedule_kernel(const int* __restrict__ cnt, int* __restrict__ meta,
                                int* __restrict__ tE, int* __restrict__ tB,
                                int* __restrict__ tV, int T, int maxTiles) {
  if (threadIdx.x != 0 || blockIdx.x != 0) return;
  int t = 0;
  for (int e = 0; e < N_EXP; e++) {
    int c = cnt[e];
    for (int r = 0; r < c && t < maxTiles; r += BM) {
      tE[t] = e; tB[t] = e * T + r; tV[t] = min(BM, c - r); t++;
    }
  }
  meta[0] = t;
}

// ---------------- GEMM1: h = relu(x_bf16 @ W1 + b1)  (grouped, 32KB LDS, 5 blk/CU) ----------------
__global__ __launch_bounds__(256, 5)
void gemm1_kernel(const unsigned short* __restrict__ xb,
                  const unsigned short* __restrict__ w1t,  // [e][FFC][D_MODEL] bf16
                  const float* __restrict__ b1,
                  const int* __restrict__ meta,
                  const int* __restrict__ tE, const int* __restrict__ tB,
                  const int* __restrict__ tV, const int* __restrict__ tokIdx,
                  unsigned short* __restrict__ h, int FFC, int chunk_off, int ncolLog2) {
  __shared__ unsigned short As[BM * BK];
  __shared__ unsigned short Bs[BN * BK];

  int total = gridDim.x;
  int L = blockIdx.x;
  int q = total >> 3, r8 = total & 7;
  int xcd = L & 7, idx = L >> 3;
  int work = (xcd < r8) ? (xcd * (q + 1) + idx) : (r8 * (q + 1) + (xcd - r8) * q + idx);
  int ncol = 1 << ncolLog2;
  int tile = work >> ncolLog2;
  int cb = work & (ncol - 1);
  if (tile >= meta[0]) return;
  int e = tE[tile], base = tB[tile], valid = tV[tile];
  int tid = threadIdx.x;

  int w = tid >> 6, lane = tid & 63;
  int lr = lane >> 3, lc = lane & 7;

  const unsigned short* panel = w1t + (size_t)e * FFC * D_MODEL;
  const unsigned short* aBase[4];
  const unsigned short* bBase[4];
  #pragma unroll
  for (int p = 0; p < 4; p++) {
    int row = (w * 4 + p) * 8 + lr;
    int tok = tokIdx[base + (row < valid ? row : valid - 1)];
    int cA = (lc - row) & 7;
    aBase[p] = xb + (size_t)tok * D_MODEL + cA * 8;
    bBase[p] = panel + (size_t)(cb * BN + row) * D_MODEL + cA * 8;
  }

  int wr = w >> 1, wc = w & 1;
  int l15 = lane & 15, l4 = lane >> 4;
  int aOff[2][4], bOff[2][4];
  #pragma unroll
  for (int kk = 0; kk < 2; kk++) {
    #pragma unroll
    for (int m = 0; m < 4; m++) {
      int row = wr * 64 + m * 16 + l15;
      int c = kk * 4 + l4;
      aOff[kk][m] = row * 64 + (((c + row) & 7) << 3);
      int col = wc * 64 + m * 16 + l15;
      bOff[kk][m] = col * 64 + (((c + col) & 7) << 3);
    }
  }

  f32x4 acc[4][4];
  #pragma unroll
  for (int m = 0; m < 4; m++)
    #pragma unroll
    for (int n = 0; n < 4; n++) acc[m][n] = (f32x4){0.f, 0.f, 0.f, 0.f};

  for (int kt = 0; kt < D_MODEL / BK; kt++) {
    #pragma unroll
    for (int p = 0; p < 4; p++)
      gl_lds16(aBase[p] + kt * BK, &As[(w * 4 + p) * 512]);
    #pragma unroll
    for (int p = 0; p < 4; p++)
      gl_lds16(bBase[p] + kt * BK, &Bs[(w * 4 + p) * 512]);
    __syncthreads();
    #pragma unroll
    for (int kk = 0; kk < 2; kk++) {
      bf16x8 a[4], b[4];
      #pragma unroll
      for (int m = 0; m < 4; m++) a[m] = *(const bf16x8*)&As[aOff[kk][m]];
      #pragma unroll
      for (int n = 0; n < 4; n++) b[n] = *(const bf16x8*)&Bs[bOff[kk][n]];
      #pragma unroll
      for (int m = 0; m < 4; m++)
        #pragma unroll
        for (int n = 0; n < 4; n++)
          acc[m][n] = __builtin_amdgcn_mfma_f32_16x16x32_bf16(a[m], b[n], acc[m][n], 0, 0, 0);
    }
    __syncthreads();
  }

  #pragma unroll
  for (int n = 0; n < 4; n++) {
    int colc = cb * BN + wc * 64 + n * 16 + l15;
    float bias = b1[(size_t)e * D_FF + chunk_off + colc];
    #pragma unroll
    for (int m = 0; m < 4; m++) {
      #pragma unroll
      for (int r = 0; r < 4; r++) {
        int row = wr * 64 + m * 16 + l4 * 4 + r;
        float v = acc[m][n][r] + bias;
        v = v > 0.f ? v : 0.f;
        h[(size_t)(tile * BM + row) * FFC + colc] = f2bf(v);
      }
    }
  }
}

// ---------------- GEMM2: out += w * (h @ W2 + b2)  (grouped, scatter, 32KB LDS, 5 blk/CU) ----------------
__global__ __launch_bounds__(256, 5)
void gemm2_kernel(const unsigned short* __restrict__ h,
                  const unsigned short* __restrict__ w2t,  // [e][D_MODEL][FFC] bf16
                  const float* __restrict__ b2,
                  const int* __restrict__ meta,
                  const int* __restrict__ tE, const int* __restrict__ tB,
                  const int* __restrict__ tV, const int* __restrict__ tokIdx,
                  const float* __restrict__ tokW,
                  float* __restrict__ out, int FFC, int chunk_off) {
  __shared__ unsigned short As[BM * BK];
  __shared__ unsigned short Bs[BN * BK];

  int total = gridDim.x;
  int L = blockIdx.x;
  int q = total >> 3, r8 = total & 7;
  int xcd = L & 7, idx = L >> 3;
  int work = (xcd < r8) ? (xcd * (q + 1) + idx) : (r8 * (q + 1) + (xcd - r8) * q + idx);
  int tile = work >> 3;          // ncol = 8
  int cb = work & 7;
  if (tile >= meta[0]) return;
  int e = tE[tile], base = tB[tile], valid = tV[tile];
  int tid = threadIdx.x;

  int w = tid >> 6, lane = tid & 63;
  int lr = lane >> 3, lc = lane & 7;

  const unsigned short* panel = w2t + (size_t)e * D_MODEL * FFC;
  const unsigned short* aBase[4];
  const unsigned short* bBase[4];
  #pragma unroll
  for (int p = 0; p < 4; p++) {
    int row = (w * 4 + p) * 8 + lr;
    int cA = (lc - row) & 7;
    aBase[p] = h + (size_t)(tile * BM + row) * FFC + cA * 8;
    bBase[p] = panel + (size_t)(cb * BN + row) * FFC + cA * 8;
  }

  int wr = w >> 1, wc = w & 1;
  int l15 = lane & 15, l4 = lane >> 4;
  int aOff[2][4], bOff[2][4];
  #pragma unroll
  for (int kk = 0; kk < 2; kk++) {
    #pragma unroll
    for (int m = 0; m < 4; m++) {
      int row = wr * 64 + m * 16 + l15;
      int c = kk * 4 + l4;
      aOff[kk][m] = row * 64 + (((c + row) & 7) << 3);
      int col = wc * 64 + m * 16 + l15;
      bOff[kk][m] = col * 64 + (((c + col) & 7) << 3);
    }
  }

  f32x4 acc[4][4];
  #pragma unroll
  for (int m = 0; m < 4; m++)
    #pragma unroll
    for (int n = 0; n < 4; n++) acc[m][n] = (f32x4){0.f, 0.f, 0.f, 0.f};

  int KT = FFC / BK;
  for (int kt = 0; kt < KT; kt++) {
    #pragma unroll
    for (int p = 0; p < 4; p++)
      gl_lds16(aBase[p] + kt * BK, &As[(w * 4 + p) * 512]);
    #pragma unroll
    for (int p = 0; p < 4; p++)
      gl_lds16(bBase[p] + kt * BK, &Bs[(w * 4 + p) * 512]);
    __syncthreads();
    #pragma unroll
    for (int kk = 0; kk < 2; kk++) {
      bf16x8 a[4], b[4];
      #pragma unroll
      for (int m = 0; m < 4; m++) a[m] = *(const bf16x8*)&As[aOff[kk][m]];
      #pragma unroll
      for (int n = 0; n < 4; n++) b[n] = *(const bf16x8*)&Bs[bOff[kk][n]];
      #pragma unroll
      for (int m = 0; m < 4; m++)
        #pragma unroll
        for (int n = 0; n < 4; n++)
          acc[m][n] = __builtin_amdgcn_mfma_f32_16x16x32_bf16(a[m], b[n], acc[m][n], 0, 0, 0);
    }
    __syncthreads();
  }

  int addBias = (chunk_off == 0) ? 1 : 0;
  #pragma unroll
  for (int n = 0; n < 4; n++) {
    int colg = cb * BN + wc * 64 + n * 16 + l15;
    float bias = addBias ? b2[(size_t)e * D_MODEL + colg] : 0.f;
    #pragma unroll
    for (int m = 0; m < 4; m++) {
      #pragma unroll
      for (int r = 0; r < 4; r++) {
        int row = wr * 64 + m * 16 + l4 * 4 + r;
        if (row < valid) {
          int tok = tokIdx[base + row];
          float wgt = tokW[base + row];
          float v = (acc[m][n][r] + bias) * wgt;
          atomicAdd(out + (size_t)tok * D_MODEL + colg, v);
        }
      }
    }
  }
}

// ---------------- host ----------------
extern "C" void kernel_launch(void* const* d_in, const int* in_sizes, int n_in,
                              void* d_out, int out_size, void* d_ws, size_t ws_size,
                              hipStream_t stream) {
  const float* x  = (const float*)d_in[0];
  const float* W1 = (const float*)d_in[1];
  const float* b1 = (const float*)d_in[2];
  const float* W2 = (const float*)d_in[3];
  const float* b2 = (const float*)d_in[4];
  const float* Wg = (const float*)d_in[5];
  const float* bg = (const float*)d_in[6];

  int T = in_sizes[0] / D_MODEL;  // 8192
  float* out = (float*)d_out;
  float* gate_out = out + (size_t)T * D_MODEL;

  char* ws = (char*)d_ws;
  int* cnt  = (int*)(ws + 0);
  int* meta = (int*)(ws + 64);
  int* tE   = (int*)(ws + 128);
  int* tB   = (int*)(ws + 1024);
  int* tV   = (int*)(ws + 2048);
  size_t off = 4096;
  int* tokIdx = (int*)(ws + off);   off += (size_t)N_EXP * T * 4;
  float* tokW = (float*)(ws + off); off += (size_t)N_EXP * T * 4;
  unsigned short* xb = (unsigned short*)(ws + off); off += (size_t)T * D_MODEL * 2;
  off = (off + 255) & ~(size_t)255;

  int maxTiles = (2 * T) / BM + N_EXP;  // 136
  int FFC = D_FF;
  while (FFC > 256 &&
         off + (size_t)FFC * (16384 + 16384 + (size_t)maxTiles * BM * 2) > ws_size)
    FFC >>= 1;

  unsigned short* w1t = (unsigned short*)(ws + off); off += (size_t)FFC * 16384;
  unsigned short* w2t = (unsigned short*)(ws + off); off += (size_t)FFC * 16384;
  unsigned short* h   = (unsigned short*)(ws + off);

  hipMemsetAsync(d_out, 0, (size_t)T * D_MODEL * sizeof(float), stream);
  hipMemsetAsync(cnt, 0, N_EXP * sizeof(int), stream);

  gating_kernel<<<(T + 3) / 4, 256, 0, stream>>>(x, Wg, bg, gate_out, xb, cnt, tokIdx, tokW, T);
  schedule_kernel<<<1, 64, 0, stream>>>(cnt, meta, tE, tB, tV, T, maxTiles);

  int ncol1 = FFC / BN;
  int ncol1Log2 = __builtin_ctz(ncol1);
  for (int c = 0; c * FFC < D_FF; c++) {
    transpose_convert_kernel<<<dim3(D_MODEL / 64, FFC / 64, N_EXP), 256, 0, stream>>>(
        W1, w1t, D_MODEL, D_FF, 0, c * FFC, FFC, (unsigned long long)D_MODEL * D_FF);
    transpose_convert_kernel<<<dim3(FFC / 64, D_MODEL / 64, N_EXP), 256, 0, stream>>>(
        W2, w2t, FFC, D_MODEL, c * FFC, 0, D_MODEL, (unsigned long long)D_FF * D_MODEL);
    gemm1_kernel<<<maxTiles * ncol1, 256, 0, stream>>>(
        xb, w1t, b1, meta, tE, tB, tV, tokIdx, h, FFC, c * FFC, ncol1Log2);
    gemm2_kernel<<<maxTiles * (D_MODEL / BN), 256, 0, stream>>>(
        h, w2t, b2, meta, tE, tB, tV, tokIdx, tokW, out, FFC, c * FFC);
  }
}

// Round 10
// 776.913 us; speedup vs baseline: 1.3402x; 1.3402x over previous
//
#include <hip/hip_runtime.h>

#define D_MODEL 1024
#define D_FF    4096
#define N_EXP   8
#define BM 128
#define BN 128
#define BK 32

typedef __attribute__((ext_vector_type(8))) short bf16x8;
typedef __attribute__((ext_vector_type(4))) float f32x4;
typedef unsigned int u32;

__device__ __forceinline__ unsigned short f2bf(float f) {
  union { float f; unsigned u; } v; v.f = f;
  unsigned r = v.u + 0x7FFFu + ((v.u >> 16) & 1u);
  return (unsigned short)(r >> 16);
}

__device__ __forceinline__ void gl_lds16(const void* g, void* l) {
  __builtin_amdgcn_global_load_lds((const __attribute__((address_space(1))) u32*)g,
                                   (__attribute__((address_space(3))) u32*)l, 16, 0, 0);
}

// ---------------- transpose + convert W -> bf16 [e][n][k] ----------------
__global__ __launch_bounds__(256)
void transpose_convert_kernel(const float* __restrict__ src, unsigned short* __restrict__ dst,
                              int Ksub, int Nsrc, int k0, int n0, int Nchunk,
                              unsigned long long eStride) {
  __shared__ u32 s32k[32][65];  // [k/2][n]
  int e = blockIdx.z;
  int kb = blockIdx.x * 64, nb = blockIdx.y * 64;
  const float* se = src + (size_t)e * eStride + (size_t)(k0 + kb) * Nsrc + (n0 + nb);
  unsigned short* de = dst + (size_t)e * Nchunk * Ksub + (size_t)nb * Ksub + kb;
  int tid = threadIdx.x;
  int kh = tid >> 4;
  int n4 = (tid & 15) * 4;
  #pragma unroll
  for (int p = 0; p < 2; p++) {
    int k = kh * 2 + p * 32;
    float4 v0 = *(const float4*)(se + (size_t)k * Nsrc + n4);
    float4 v1 = *(const float4*)(se + (size_t)(k + 1) * Nsrc + n4);
    #pragma unroll
    for (int j = 0; j < 4; j++) {
      u32 pk = (u32)f2bf(((const float*)&v0)[j]) |
               ((u32)f2bf(((const float*)&v1)[j]) << 16);
      s32k[k >> 1][n4 + j] = pk;
    }
  }
  __syncthreads();
  #pragma unroll
  for (int c = 0; c < 2; c++) {
    int id = tid + c * 256;
    int n = id >> 3, kc = id & 7;
    uint4 o;
    o.x = s32k[kc * 4 + 0][n];
    o.y = s32k[kc * 4 + 1][n];
    o.z = s32k[kc * 4 + 2][n];
    o.w = s32k[kc * 4 + 3][n];
    *(uint4*)(de + (size_t)n * Ksub + kc * 8) = o;
  }
}

// ---------------- gating (+ fused x->bf16 convert): 1 wave per token ----------------
__global__ void gating_kernel(const float* __restrict__ x,
                              const float* __restrict__ Wg,
                              const float* __restrict__ bg,
                              float* __restrict__ gate_out,
                              unsigned short* __restrict__ xb,
                              int* __restrict__ cnt,
                              int* __restrict__ tokIdx,
                              float* __restrict__ tokW, int T) {
  int wv = threadIdx.x >> 6, lane = threadIdx.x & 63;
  int t = blockIdx.x * 4 + wv;
  if (t >= T) return;
  const float* xr = x + (size_t)t * D_MODEL + lane * 16;
  float acc[N_EXP];
  #pragma unroll
  for (int e = 0; e < N_EXP; e++) acc[e] = 0.f;
  ushort4 xc[4];
  #pragma unroll
  for (int q = 0; q < 4; q++) {
    float4 xv = *(const float4*)(xr + q * 4);
    xc[q].x = f2bf(xv.x); xc[q].y = f2bf(xv.y);
    xc[q].z = f2bf(xv.z); xc[q].w = f2bf(xv.w);
    #pragma unroll
    for (int r = 0; r < 4; r++) {
      float xs = ((const float*)&xv)[r];
      const float* wrow = Wg + (size_t)(lane * 16 + q * 4 + r) * N_EXP;
      float4 wa = *(const float4*)wrow;
      float4 wb = *(const float4*)(wrow + 4);
      acc[0] += xs * wa.x; acc[1] += xs * wa.y; acc[2] += xs * wa.z; acc[3] += xs * wa.w;
      acc[4] += xs * wb.x; acc[5] += xs * wb.y; acc[6] += xs * wb.z; acc[7] += xs * wb.w;
    }
  }
  unsigned short* xbr = xb + (size_t)t * D_MODEL + lane * 16;
  #pragma unroll
  for (int q = 0; q < 4; q++) *(ushort4*)(xbr + q * 4) = xc[q];
  #pragma unroll
  for (int off = 32; off > 0; off >>= 1) {
    #pragma unroll
    for (int e = 0; e < N_EXP; e++) acc[e] += __shfl_xor(acc[e], off);
  }
  if (lane == 0) {
    float l[N_EXP], p[N_EXP];
    float m = -1e30f;
    #pragma unroll
    for (int e = 0; e < N_EXP; e++) { l[e] = acc[e] + bg[e]; m = fmaxf(m, l[e]); }
    float s = 0.f;
    #pragma unroll
    for (int e = 0; e < N_EXP; e++) { p[e] = __expf(l[e] - m); s += p[e]; }
    float inv = 1.f / s;
    #pragma unroll
    for (int e = 0; e < N_EXP; e++) { p[e] *= inv; gate_out[(size_t)t * N_EXP + e] = p[e]; }
    int e1 = 0;
    #pragma unroll
    for (int e = 1; e < N_EXP; e++) if (p[e] > p[e1]) e1 = e;
    int e2 = (e1 == 0) ? 1 : 0;
    #pragma unroll
    for (int e = 0; e < N_EXP; e++) if (e != e1 && p[e] > p[e2]) e2 = e;
    int pos = atomicAdd(cnt + e1, 1);
    tokIdx[(size_t)e1 * T + pos] = t; tokW[(size_t)e1 * T + pos] = p[e1];
    pos = atomicAdd(cnt + e2, 1);
    tokIdx[(size_t)e2 * T + pos] = t; tokW[(size_t)e2 * T + pos] = p[e2];
  }
}

// ---------------- schedule: build row-tile table ----------------
__global__ void schedule_kernel(const int* __restrict__ cnt, int* __restrict__ meta,
                                int* __restrict__ tE, int* __restrict__ tB,
                                int* __restrict__ tV, int T, int maxTiles) {
  if (threadIdx.x != 0 || blockIdx.x != 0) return;
  int t = 0;
  for (int e = 0; e < N_EXP; e++) {
    int c = cnt[e];
    for (int r = 0; r < c && t < maxTiles; r += BM) {
      tE[t] = e; tB[t] = e * T + r; tV[t] = min(BM, c - r); t++;
    }
  }
  meta[0] = t;
}

// ======== triple-buffered BK=32 pipeline ========
// Per buffer b (ushort idx, base b*8192): A rows [0,4096), B rows [4096,8192).
// Row = 32 ushorts (64B, 4 chunks of 16B). LDS chunk c holds global chunk
// (c-(r>>1))&3; read at c_eff=(l4+(r>>1))&3 -> global chunk l4. 2-way banks.
#define STAGE(b, kt) { _Pragma("unroll") for (int p_ = 0; p_ < 2; p_++) { \
    gl_lds16(srcA[p_] + (size_t)(kt) * BK, &LDSU[(b) * 8192 + (w * 32 + p_ * 16) * 32]); \
    gl_lds16(srcB[p_] + (size_t)(kt) * BK, &LDSU[(b) * 8192 + 4096 + (w * 32 + p_ * 16) * 32]); } }

#define COMPUTE(b) { \
    bf16x8 ra[4], rb[4]; \
    _Pragma("unroll") for (int m_ = 0; m_ < 4; m_++) { \
      int row_ = wr * 64 + m_ * 16 + l15; \
      ra[m_] = *(const bf16x8*)&LDSU[(b) * 8192 + row_ * 32 + (((l4 + (row_ >> 1)) & 3) << 3)]; } \
    _Pragma("unroll") for (int n_ = 0; n_ < 4; n_++) { \
      int rb_ = wc * 64 + n_ * 16 + l15; \
      rb[n_] = *(const bf16x8*)&LDSU[(b) * 8192 + 4096 + rb_ * 32 + (((l4 + (rb_ >> 1)) & 3) << 3)]; } \
    _Pragma("unroll") for (int m_ = 0; m_ < 4; m_++) \
      _Pragma("unroll") for (int n_ = 0; n_ < 4; n_++) \
        acc[m_][n_] = __builtin_amdgcn_mfma_f32_16x16x32_bf16(ra[m_], rb[n_], acc[m_][n_], 0, 0, 0); }

#define BAR() { __builtin_amdgcn_s_barrier(); asm volatile("" ::: "memory"); }
#define WAITVM(N) asm volatile("s_waitcnt vmcnt(" #N ")" ::: "memory");

#define PIPELINE(NT) \
  STAGE(0, 0); STAGE(1, 1); \
  for (int kt = 0; kt < (NT) - 2; kt++) { \
    STAGE((kt + 2) % 3, kt + 2); \
    WAITVM(8); BAR(); \
    COMPUTE(kt % 3); \
    BAR(); \
  } \
  WAITVM(4); BAR(); COMPUTE(((NT) - 2) % 3); BAR(); \
  WAITVM(0); BAR(); COMPUTE(((NT) - 1) % 3);

// ---------------- GEMM1: h = relu(x_bf16 @ W1 + b1)  (grouped, 3-buf pipeline) ----------------
__global__ __launch_bounds__(256)
void gemm1_kernel(const unsigned short* __restrict__ xb,
                  const unsigned short* __restrict__ w1t,  // [e][FFC][D_MODEL] bf16
                  const float* __restrict__ b1,
                  const int* __restrict__ meta,
                  const int* __restrict__ tE, const int* __restrict__ tB,
                  const int* __restrict__ tV, const int* __restrict__ tokIdx,
                  unsigned short* __restrict__ h, int FFC, int chunk_off, int ncolLog2) {
  __shared__ unsigned short LDSU[24576];  // 48 KiB = 3 buffers

  int total = gridDim.x;
  int L = blockIdx.x;
  int q = total >> 3, r8 = total & 7;
  int xcd = L & 7, idx = L >> 3;
  int work = (xcd < r8) ? (xcd * (q + 1) + idx) : (r8 * (q + 1) + (xcd - r8) * q + idx);
  int ncol = 1 << ncolLog2;
  int tile = work >> ncolLog2;
  int cb = work & (ncol - 1);
  if (tile >= meta[0]) return;
  int e = tE[tile], base = tB[tile], valid = tV[tile];
  int tid = threadIdx.x;

  int w = tid >> 6, lane = tid & 63;
  int wr = w >> 1, wc = w & 1;
  int l15 = lane & 15, l4 = lane >> 4;
  int lrow = lane >> 2, lch = lane & 3;

  const unsigned short* panel = w1t + (size_t)e * FFC * D_MODEL;
  const unsigned short* srcA[2];
  const unsigned short* srcB[2];
  #pragma unroll
  for (int p = 0; p < 2; p++) {
    int r = w * 32 + p * 16 + lrow;
    int tok = tokIdx[base + (r < valid ? r : valid - 1)];
    int g = (lch - (r >> 1)) & 3;
    srcA[p] = xb + (size_t)tok * D_MODEL + g * 8;
    srcB[p] = panel + (size_t)(cb * BN + r) * D_MODEL + g * 8;
  }

  f32x4 acc[4][4];
  #pragma unroll
  for (int m = 0; m < 4; m++)
    #pragma unroll
    for (int n = 0; n < 4; n++) acc[m][n] = (f32x4){0.f, 0.f, 0.f, 0.f};

  PIPELINE(D_MODEL / BK);  // 32

  #pragma unroll
  for (int n = 0; n < 4; n++) {
    int colc = cb * BN + wc * 64 + n * 16 + l15;
    float bias = b1[(size_t)e * D_FF + chunk_off + colc];
    #pragma unroll
    for (int m = 0; m < 4; m++) {
      #pragma unroll
      for (int r = 0; r < 4; r++) {
        int row = wr * 64 + m * 16 + l4 * 4 + r;
        float v = acc[m][n][r] + bias;
        v = v > 0.f ? v : 0.f;
        h[(size_t)(tile * BM + row) * FFC + colc] = f2bf(v);
      }
    }
  }
}

// ---------------- GEMM2: out += w * (h @ W2 + b2)  (grouped, scatter, 3-buf pipeline) ----------------
__global__ __launch_bounds__(256)
void gemm2_kernel(const unsigned short* __restrict__ h,
                  const unsigned short* __restrict__ w2t,  // [e][D_MODEL][FFC] bf16
                  const float* __restrict__ b2,
                  const int* __restrict__ meta,
                  const int* __restrict__ tE, const int* __restrict__ tB,
                  const int* __restrict__ tV, const int* __restrict__ tokIdx,
                  const float* __restrict__ tokW,
                  float* __restrict__ out, int FFC, int chunk_off) {
  __shared__ unsigned short LDSU[24576];

  int total = gridDim.x;
  int L = blockIdx.x;
  int q = total >> 3, r8 = total & 7;
  int xcd = L & 7, idx = L >> 3;
  int work = (xcd < r8) ? (xcd * (q + 1) + idx) : (r8 * (q + 1) + (xcd - r8) * q + idx);
  int tile = work >> 3;          // ncol = 8
  int cb = work & 7;
  if (tile >= meta[0]) return;
  int e = tE[tile], base = tB[tile], valid = tV[tile];
  int tid = threadIdx.x;

  int w = tid >> 6, lane = tid & 63;
  int wr = w >> 1, wc = w & 1;
  int l15 = lane & 15, l4 = lane >> 4;
  int lrow = lane >> 2, lch = lane & 3;

  const unsigned short* panel = w2t + (size_t)e * D_MODEL * FFC;
  const unsigned short* srcA[2];
  const unsigned short* srcB[2];
  #pragma unroll
  for (int p = 0; p < 2; p++) {
    int r = w * 32 + p * 16 + lrow;
    int g = (lch - (r >> 1)) & 3;
    srcA[p] = h + (size_t)(tile * BM + r) * FFC + g * 8;
    srcB[p] = panel + (size_t)(cb * BN + r) * FFC + g * 8;
  }

  f32x4 acc[4][4];
  #pragma unroll
  for (int m = 0; m < 4; m++)
    #pragma unroll
    for (int n = 0; n < 4; n++) acc[m][n] = (f32x4){0.f, 0.f, 0.f, 0.f};

  PIPELINE(FFC / BK);  // 128

  int addBias = (chunk_off == 0) ? 1 : 0;
  #pragma unroll
  for (int n = 0; n < 4; n++) {
    int colg = cb * BN + wc * 64 + n * 16 + l15;
    float bias = addBias ? b2[(size_t)e * D_MODEL + colg] : 0.f;
    #pragma unroll
    for (int m = 0; m < 4; m++) {
      #pragma unroll
      for (int r = 0; r < 4; r++) {
        int row = wr * 64 + m * 16 + l4 * 4 + r;
        if (row < valid) {
          int tok = tokIdx[base + row];
          float wgt = tokW[base + row];
          float v = (acc[m][n][r] + bias) * wgt;
          atomicAdd(out + (size_t)tok * D_MODEL + colg, v);
        }
      }
    }
  }
}

// ---------------- host ----------------
extern "C" void kernel_launch(void* const* d_in, const int* in_sizes, int n_in,
                              void* d_out, int out_size, void* d_ws, size_t ws_size,
                              hipStream_t stream) {
  const float* x  = (const float*)d_in[0];
  const float* W1 = (const float*)d_in[1];
  const float* b1 = (const float*)d_in[2];
  const float* W2 = (const float*)d_in[3];
  const float* b2 = (const float*)d_in[4];
  const float* Wg = (const float*)d_in[5];
  const float* bg = (const float*)d_in[6];

  int T = in_sizes[0] / D_MODEL;  // 8192
  float* out = (float*)d_out;
  float* gate_out = out + (size_t)T * D_MODEL;

  char* ws = (char*)d_ws;
  int* cnt  = (int*)(ws + 0);
  int* meta = (int*)(ws + 64);
  int* tE   = (int*)(ws + 128);
  int* tB   = (int*)(ws + 1024);
  int* tV   = (int*)(ws + 2048);
  size_t off = 4096;
  int* tokIdx = (int*)(ws + off);   off += (size_t)N_EXP * T * 4;
  float* tokW = (float*)(ws + off); off += (size_t)N_EXP * T * 4;
  unsigned short* xb = (unsigned short*)(ws + off); off += (size_t)T * D_MODEL * 2;
  off = (off + 255) & ~(size_t)255;

  int maxTiles = (2 * T) / BM + N_EXP;  // 136
  int FFC = D_FF;
  while (FFC > 256 &&
         off + (size_t)FFC * (16384 + 16384 + (size_t)maxTiles * BM * 2) > ws_size)
    FFC >>= 1;

  unsigned short* w1t = (unsigned short*)(ws + off); off += (size_t)FFC * 16384;
  unsigned short* w2t = (unsigned short*)(ws + off); off += (size_t)FFC * 16384;
  unsigned short* h   = (unsigned short*)(ws + off);

  hipMemsetAsync(d_out, 0, (size_t)T * D_MODEL * sizeof(float), stream);
  hipMemsetAsync(cnt, 0, N_EXP * sizeof(int), stream);

  gating_kernel<<<(T + 3) / 4, 256, 0, stream>>>(x, Wg, bg, gate_out, xb, cnt, tokIdx, tokW, T);
  schedule_kernel<<<1, 64, 0, stream>>>(cnt, meta, tE, tB, tV, T, maxTiles);

  int ncol1 = FFC / BN;
  int ncol1Log2 = __builtin_ctz(ncol1);
  for (int c = 0; c * FFC < D_FF; c++) {
    transpose_convert_kernel<<<dim3(D_MODEL / 64, FFC / 64, N_EXP), 256, 0, stream>>>(
        W1, w1t, D_MODEL, D_FF, 0, c * FFC, FFC, (unsigned long long)D_MODEL * D_FF);
    transpose_convert_kernel<<<dim3(FFC / 64, D_MODEL / 64, N_EXP), 256, 0, stream>>>(
        W2, w2t, FFC, D_MODEL, c * FFC, 0, D_MODEL, (unsigned long long)D_FF * D_MODEL);
    gemm1_kernel<<<maxTiles * ncol1, 256, 0, stream>>>(
        xb, w1t, b1, meta, tE, tB, tV, tokIdx, h, FFC, c * FFC, ncol1Log2);
    gemm2_kernel<<<maxTiles * (D_MODEL / BN), 256, 0, stream>>>(
        h, w2t, b2, meta, tE, tB, tV, tokIdx, tokW, out, FFC, c * FFC);
  }
}

// Round 11
// 739.454 us; speedup vs baseline: 1.4080x; 1.0507x over previous
//
#include <hip/hip_runtime.h>

#define D_MODEL 1024
#define D_FF    4096
#define N_EXP   8
#define BM 128
#define BN 128
#define BK 32

typedef __attribute__((ext_vector_type(8))) short bf16x8;
typedef __attribute__((ext_vector_type(4))) float f32x4;
typedef unsigned int u32;

__device__ __forceinline__ unsigned short f2bf(float f) {
  union { float f; unsigned u; } v; v.f = f;
  unsigned r = v.u + 0x7FFFu + ((v.u >> 16) & 1u);
  return (unsigned short)(r >> 16);
}

__device__ __forceinline__ void gl_lds16(const void* g, void* l) {
  __builtin_amdgcn_global_load_lds((const __attribute__((address_space(1))) u32*)g,
                                   (__attribute__((address_space(3))) u32*)l, 16, 0, 0);
}

// ---------------- transpose + convert W -> bf16 [e][n][k] ----------------
__global__ __launch_bounds__(256)
void transpose_convert_kernel(const float* __restrict__ src, unsigned short* __restrict__ dst,
                              int Ksub, int Nsrc,
                              unsigned long long eStride) {
  __shared__ u32 s32k[32][65];  // [k/2][n]
  int e = blockIdx.z;
  int kb = blockIdx.x * 64, nb = blockIdx.y * 64;
  const float* se = src + (size_t)e * eStride + (size_t)kb * Nsrc + nb;
  unsigned short* de = dst + (size_t)e * (size_t)Nsrc * Ksub + (size_t)nb * Ksub + kb;
  int tid = threadIdx.x;
  int kh = tid >> 4;
  int n4 = (tid & 15) * 4;
  #pragma unroll
  for (int p = 0; p < 2; p++) {
    int k = kh * 2 + p * 32;
    float4 v0 = *(const float4*)(se + (size_t)k * Nsrc + n4);
    float4 v1 = *(const float4*)(se + (size_t)(k + 1) * Nsrc + n4);
    #pragma unroll
    for (int j = 0; j < 4; j++) {
      u32 pk = (u32)f2bf(((const float*)&v0)[j]) |
               ((u32)f2bf(((const float*)&v1)[j]) << 16);
      s32k[k >> 1][n4 + j] = pk;
    }
  }
  __syncthreads();
  #pragma unroll
  for (int c = 0; c < 2; c++) {
    int id = tid + c * 256;
    int n = id >> 3, kc = id & 7;
    uint4 o;
    o.x = s32k[kc * 4 + 0][n];
    o.y = s32k[kc * 4 + 1][n];
    o.z = s32k[kc * 4 + 2][n];
    o.w = s32k[kc * 4 + 3][n];
    *(uint4*)(de + (size_t)n * Ksub + kc * 8) = o;
  }
}

// ---------------- gating (+ fused x->bf16 convert): 1 wave per token ----------------
__global__ void gating_kernel(const float* __restrict__ x,
                              const float* __restrict__ Wg,
                              const float* __restrict__ bg,
                              float* __restrict__ gate_out,
                              unsigned short* __restrict__ xb,
                              int* __restrict__ cnt,
                              int* __restrict__ tokIdx,
                              float* __restrict__ tokW, int T) {
  int wv = threadIdx.x >> 6, lane = threadIdx.x & 63;
  int t = blockIdx.x * 4 + wv;
  if (t >= T) return;
  const float* xr = x + (size_t)t * D_MODEL + lane * 16;
  float acc[N_EXP];
  #pragma unroll
  for (int e = 0; e < N_EXP; e++) acc[e] = 0.f;
  ushort4 xc[4];
  #pragma unroll
  for (int q = 0; q < 4; q++) {
    float4 xv = *(const float4*)(xr + q * 4);
    xc[q].x = f2bf(xv.x); xc[q].y = f2bf(xv.y);
    xc[q].z = f2bf(xv.z); xc[q].w = f2bf(xv.w);
    #pragma unroll
    for (int r = 0; r < 4; r++) {
      float xs = ((const float*)&xv)[r];
      const float* wrow = Wg + (size_t)(lane * 16 + q * 4 + r) * N_EXP;
      float4 wa = *(const float4*)wrow;
      float4 wb = *(const float4*)(wrow + 4);
      acc[0] += xs * wa.x; acc[1] += xs * wa.y; acc[2] += xs * wa.z; acc[3] += xs * wa.w;
      acc[4] += xs * wb.x; acc[5] += xs * wb.y; acc[6] += xs * wb.z; acc[7] += xs * wb.w;
    }
  }
  unsigned short* xbr = xb + (size_t)t * D_MODEL + lane * 16;
  #pragma unroll
  for (int q = 0; q < 4; q++) *(ushort4*)(xbr + q * 4) = xc[q];
  #pragma unroll
  for (int off = 32; off > 0; off >>= 1) {
    #pragma unroll
    for (int e = 0; e < N_EXP; e++) acc[e] += __shfl_xor(acc[e], off);
  }
  if (lane == 0) {
    float l[N_EXP], p[N_EXP];
    float m = -1e30f;
    #pragma unroll
    for (int e = 0; e < N_EXP; e++) { l[e] = acc[e] + bg[e]; m = fmaxf(m, l[e]); }
    float s = 0.f;
    #pragma unroll
    for (int e = 0; e < N_EXP; e++) { p[e] = __expf(l[e] - m); s += p[e]; }
    float inv = 1.f / s;
    #pragma unroll
    for (int e = 0; e < N_EXP; e++) { p[e] *= inv; gate_out[(size_t)t * N_EXP + e] = p[e]; }
    int e1 = 0;
    #pragma unroll
    for (int e = 1; e < N_EXP; e++) if (p[e] > p[e1]) e1 = e;
    int e2 = (e1 == 0) ? 1 : 0;
    #pragma unroll
    for (int e = 0; e < N_EXP; e++) if (e != e1 && p[e] > p[e2]) e2 = e;
    int pos = atomicAdd(cnt + e1, 1);
    tokIdx[(size_t)e1 * T + pos] = t; tokW[(size_t)e1 * T + pos] = p[e1];
    pos = atomicAdd(cnt + e2, 1);
    tokIdx[(size_t)e2 * T + pos] = t; tokW[(size_t)e2 * T + pos] = p[e2];
  }
}

// ---------------- schedule: build row-tile table ----------------
__global__ void schedule_kernel(const int* __restrict__ cnt, int* __restrict__ meta,
                                int* __restrict__ tE, int* __restrict__ tB,
                                int* __restrict__ tV, int T, int maxTiles) {
  if (threadIdx.x != 0 || blockIdx.x != 0) return;
  int t = 0;
  for (int e = 0; e < N_EXP; e++) {
    int c = cnt[e];
    for (int r = 0; r < c && t < maxTiles; r += BM) {
      tE[t] = e; tB[t] = e * T + r; tV[t] = min(BM, c - r); t++;
    }
  }
  meta[0] = t;
}

// ======== triple-buffered BK=32 pipeline, modulo-free (compile-time NT) ========
// Buffer b (ushort idx, base b*8192): A rows [0,4096), B rows [4096,8192).
// Row = 32 ushorts (64B, 4 chunks of 16B). LDS chunk c holds global chunk
// (c-(r>>1))&3; read at c_eff=(l4+(r>>1))&3 -> global chunk l4. 2-way banks.
#define STAGE(b, kt) { _Pragma("unroll") for (int p_ = 0; p_ < 2; p_++) { \
    gl_lds16(srcA[p_] + (size_t)(kt) * BK, &LDSU[(b) * 8192 + (w * 32 + p_ * 16) * 32]); \
    gl_lds16(srcB[p_] + (size_t)(kt) * BK, &LDSU[(b) * 8192 + 4096 + (w * 32 + p_ * 16) * 32]); } }

#define COMPUTE(b) { \
    bf16x8 ra[4], rb[4]; \
    _Pragma("unroll") for (int m_ = 0; m_ < 4; m_++) { \
      int row_ = wr * 64 + m_ * 16 + l15; \
      ra[m_] = *(const bf16x8*)&LDSU[(b) * 8192 + row_ * 32 + (((l4 + (row_ >> 1)) & 3) << 3)]; } \
    _Pragma("unroll") for (int n_ = 0; n_ < 4; n_++) { \
      int rb_ = wc * 64 + n_ * 16 + l15; \
      rb[n_] = *(const bf16x8*)&LDSU[(b) * 8192 + 4096 + rb_ * 32 + (((l4 + (rb_ >> 1)) & 3) << 3)]; } \
    _Pragma("unroll") for (int m_ = 0; m_ < 4; m_++) \
      _Pragma("unroll") for (int n_ = 0; n_ < 4; n_++) \
        acc[m_][n_] = __builtin_amdgcn_mfma_f32_16x16x32_bf16(ra[m_], rb[n_], acc[m_][n_], 0, 0, 0); }

#define BAR() { __builtin_amdgcn_s_barrier(); asm volatile("" ::: "memory"); }
#define WAITVM(N) asm volatile("s_waitcnt vmcnt(" #N ")" ::: "memory");

// NT must satisfy (NT-2) % 3 == 0 (holds for 32 and 128).
#define PIPE3(NT) \
  STAGE(0, 0); STAGE(1, 1); \
  for (int it = 0; it < ((NT) - 2) / 3; it++) { \
    int kt = 3 * it; \
    STAGE(2, kt + 2); WAITVM(8); BAR(); COMPUTE(0); BAR(); \
    STAGE(0, kt + 3); WAITVM(8); BAR(); COMPUTE(1); BAR(); \
    STAGE(1, kt + 4); WAITVM(8); BAR(); COMPUTE(2); BAR(); \
  } \
  WAITVM(4); BAR(); COMPUTE(0); BAR(); \
  WAITVM(0); BAR(); COMPUTE(1);

// ---------------- GEMM1: h = relu(x_bf16 @ W1 + b1)  (grouped, 3-buf pipeline) ----------------
__global__ __launch_bounds__(256)
void gemm1_kernel(const unsigned short* __restrict__ xb,
                  const unsigned short* __restrict__ w1t,  // [e][D_FF][D_MODEL] bf16
                  const float* __restrict__ b1,
                  const int* __restrict__ meta,
                  const int* __restrict__ tE, const int* __restrict__ tB,
                  const int* __restrict__ tV, const int* __restrict__ tokIdx,
                  unsigned short* __restrict__ h) {
  __shared__ unsigned short LDSU[24576];  // 48 KiB = 3 buffers

  int total = gridDim.x;
  int L = blockIdx.x;
  int q = total >> 3, r8 = total & 7;
  int xcd = L & 7, idx = L >> 3;
  int work = (xcd < r8) ? (xcd * (q + 1) + idx) : (r8 * (q + 1) + (xcd - r8) * q + idx);
  int tile = work >> 5;          // ncol = D_FF/BN = 32
  int cb = work & 31;
  if (tile >= meta[0]) return;
  int e = tE[tile], base = tB[tile], valid = tV[tile];
  int tid = threadIdx.x;

  int w = tid >> 6, lane = tid & 63;
  int wr = w >> 1, wc = w & 1;
  int l15 = lane & 15, l4 = lane >> 4;
  int lrow = lane >> 2, lch = lane & 3;

  const unsigned short* panel = w1t + (size_t)e * D_FF * D_MODEL;
  const unsigned short* srcA[2];
  const unsigned short* srcB[2];
  #pragma unroll
  for (int p = 0; p < 2; p++) {
    int r = w * 32 + p * 16 + lrow;
    int tok = tokIdx[base + (r < valid ? r : valid - 1)];
    int g = (lch - (r >> 1)) & 3;
    srcA[p] = xb + (size_t)tok * D_MODEL + g * 8;
    srcB[p] = panel + (size_t)(cb * BN + r) * D_MODEL + g * 8;
  }

  f32x4 acc[4][4];
  #pragma unroll
  for (int m = 0; m < 4; m++)
    #pragma unroll
    for (int n = 0; n < 4; n++) acc[m][n] = (f32x4){0.f, 0.f, 0.f, 0.f};

  PIPE3(D_MODEL / BK);  // 32 -> 10 triples + drain

  #pragma unroll
  for (int n = 0; n < 4; n++) {
    int colc = cb * BN + wc * 64 + n * 16 + l15;
    float bias = b1[(size_t)e * D_FF + colc];
    #pragma unroll
    for (int m = 0; m < 4; m++) {
      #pragma unroll
      for (int r = 0; r < 4; r++) {
        int row = wr * 64 + m * 16 + l4 * 4 + r;
        float v = acc[m][n][r] + bias;
        v = v > 0.f ? v : 0.f;
        h[(size_t)(tile * BM + row) * D_FF + colc] = f2bf(v);
      }
    }
  }
}

// ---------------- GEMM2: out += w * (h @ W2 + b2)  (grouped, scatter, 3-buf pipeline) ----------------
__global__ __launch_bounds__(256)
void gemm2_kernel(const unsigned short* __restrict__ h,
                  const unsigned short* __restrict__ w2t,  // [e][D_MODEL][D_FF] bf16
                  const float* __restrict__ b2,
                  const int* __restrict__ meta,
                  const int* __restrict__ tE, const int* __restrict__ tB,
                  const int* __restrict__ tV, const int* __restrict__ tokIdx,
                  const float* __restrict__ tokW,
                  float* __restrict__ out) {
  __shared__ unsigned short LDSU[24576];

  int total = gridDim.x;
  int L = blockIdx.x;
  int q = total >> 3, r8 = total & 7;
  int xcd = L & 7, idx = L >> 3;
  int work = (xcd < r8) ? (xcd * (q + 1) + idx) : (r8 * (q + 1) + (xcd - r8) * q + idx);
  int tile = work >> 3;          // ncol = D_MODEL/BN = 8
  int cb = work & 7;
  if (tile >= meta[0]) return;
  int e = tE[tile], base = tB[tile], valid = tV[tile];
  int tid = threadIdx.x;

  int w = tid >> 6, lane = tid & 63;
  int wr = w >> 1, wc = w & 1;
  int l15 = lane & 15, l4 = lane >> 4;
  int lrow = lane >> 2, lch = lane & 3;

  const unsigned short* panel = w2t + (size_t)e * D_MODEL * D_FF;
  const unsigned short* srcA[2];
  const unsigned short* srcB[2];
  #pragma unroll
  for (int p = 0; p < 2; p++) {
    int r = w * 32 + p * 16 + lrow;
    int g = (lch - (r >> 1)) & 3;
    srcA[p] = h + (size_t)(tile * BM + r) * D_FF + g * 8;
    srcB[p] = panel + (size_t)(cb * BN + r) * D_FF + g * 8;
  }

  f32x4 acc[4][4];
  #pragma unroll
  for (int m = 0; m < 4; m++)
    #pragma unroll
    for (int n = 0; n < 4; n++) acc[m][n] = (f32x4){0.f, 0.f, 0.f, 0.f};

  PIPE3(D_FF / BK);  // 128 -> 42 triples + drain

  float biasv[4];
  #pragma unroll
  for (int n = 0; n < 4; n++)
    biasv[n] = b2[(size_t)e * D_MODEL + cb * BN + wc * 64 + n * 16 + l15];

  #pragma unroll
  for (int m = 0; m < 4; m++) {
    #pragma unroll
    for (int r = 0; r < 4; r++) {
      int row = wr * 64 + m * 16 + l4 * 4 + r;
      if (row < valid) {
        int tok = tokIdx[base + row];
        float wgt = tokW[base + row];
        float* orow = out + (size_t)tok * D_MODEL + cb * BN + wc * 64 + l15;
        #pragma unroll
        for (int n = 0; n < 4; n++)
          atomicAdd(orow + n * 16, (acc[m][n][r] + biasv[n]) * wgt);
      }
    }
  }
}

// ---------------- host ----------------
extern "C" void kernel_launch(void* const* d_in, const int* in_sizes, int n_in,
                              void* d_out, int out_size, void* d_ws, size_t ws_size,
                              hipStream_t stream) {
  const float* x  = (const float*)d_in[0];
  const float* W1 = (const float*)d_in[1];
  const float* b1 = (const float*)d_in[2];
  const float* W2 = (const float*)d_in[3];
  const float* b2 = (const float*)d_in[4];
  const float* Wg = (const float*)d_in[5];
  const float* bg = (const float*)d_in[6];

  int T = in_sizes[0] / D_MODEL;  // 8192
  float* out = (float*)d_out;
  float* gate_out = out + (size_t)T * D_MODEL;

  char* ws = (char*)d_ws;
  int* cnt  = (int*)(ws + 0);
  int* meta = (int*)(ws + 64);
  int* tE   = (int*)(ws + 128);
  int* tB   = (int*)(ws + 1024);
  int* tV   = (int*)(ws + 2048);
  size_t off = 4096;
  int* tokIdx = (int*)(ws + off);   off += (size_t)N_EXP * T * 4;
  float* tokW = (float*)(ws + off); off += (size_t)N_EXP * T * 4;
  unsigned short* xb = (unsigned short*)(ws + off); off += (size_t)T * D_MODEL * 2;
  off = (off + 255) & ~(size_t)255;

  int maxTiles = (2 * T) / BM + N_EXP;  // 136

  unsigned short* w1t = (unsigned short*)(ws + off); off += (size_t)N_EXP * D_MODEL * D_FF * 2;
  unsigned short* w2t = (unsigned short*)(ws + off); off += (size_t)N_EXP * D_MODEL * D_FF * 2;
  unsigned short* h   = (unsigned short*)(ws + off);

  hipMemsetAsync(d_out, 0, (size_t)T * D_MODEL * sizeof(float), stream);
  hipMemsetAsync(cnt, 0, N_EXP * sizeof(int), stream);

  gating_kernel<<<(T + 3) / 4, 256, 0, stream>>>(x, Wg, bg, gate_out, xb, cnt, tokIdx, tokW, T);
  schedule_kernel<<<1, 64, 0, stream>>>(cnt, meta, tE, tB, tV, T, maxTiles);

  transpose_convert_kernel<<<dim3(D_MODEL / 64, D_FF / 64, N_EXP), 256, 0, stream>>>(
      W1, w1t, D_MODEL, D_FF, (unsigned long long)D_MODEL * D_FF);
  transpose_convert_kernel<<<dim3(D_FF / 64, D_MODEL / 64, N_EXP), 256, 0, stream>>>(
      W2, w2t, D_FF, D_MODEL, (unsigned long long)D_FF * D_MODEL);

  gemm1_kernel<<<maxTiles * (D_FF / BN), 256, 0, stream>>>(
      xb, w1t, b1, meta, tE, tB, tV, tokIdx, h);
  gemm2_kernel<<<maxTiles * (D_MODEL / BN), 256, 0, stream>>>(
      h, w2t, b2, meta, tE, tB, tV, tokIdx, tokW, out);
}

// Round 12
// 733.754 us; speedup vs baseline: 1.4190x; 1.0078x over previous
//
#include <hip/hip_runtime.h>

#define D_MODEL 1024
#define D_FF    4096
#define N_EXP   8
#define BM 128
#define BN 128
#define BK 32

typedef __attribute__((ext_vector_type(8))) short bf16x8;
typedef __attribute__((ext_vector_type(4))) float f32x4;
typedef unsigned int u32;

__device__ __forceinline__ unsigned short f2bf(float f) {
  union { float f; unsigned u; } v; v.f = f;
  unsigned r = v.u + 0x7FFFu + ((v.u >> 16) & 1u);
  return (unsigned short)(r >> 16);
}

__device__ __forceinline__ void gl_lds16(const void* g, void* l) {
  __builtin_amdgcn_global_load_lds((const __attribute__((address_space(1))) u32*)g,
                                   (__attribute__((address_space(3))) u32*)l, 16, 0, 0);
}

// ---------------- transpose + convert W -> bf16 [e][n][k] ----------------
__global__ __launch_bounds__(256)
void transpose_convert_kernel(const float* __restrict__ src, unsigned short* __restrict__ dst,
                              int Ksub, int Nsrc,
                              unsigned long long eStride) {
  __shared__ u32 s32k[32][65];  // [k/2][n]
  int e = blockIdx.z;
  int kb = blockIdx.x * 64, nb = blockIdx.y * 64;
  const float* se = src + (size_t)e * eStride + (size_t)kb * Nsrc + nb;
  unsigned short* de = dst + (size_t)e * (size_t)Nsrc * Ksub + (size_t)nb * Ksub + kb;
  int tid = threadIdx.x;
  int kh = tid >> 4;
  int n4 = (tid & 15) * 4;
  #pragma unroll
  for (int p = 0; p < 2; p++) {
    int k = kh * 2 + p * 32;
    float4 v0 = *(const float4*)(se + (size_t)k * Nsrc + n4);
    float4 v1 = *(const float4*)(se + (size_t)(k + 1) * Nsrc + n4);
    #pragma unroll
    for (int j = 0; j < 4; j++) {
      u32 pk = (u32)f2bf(((const float*)&v0)[j]) |
               ((u32)f2bf(((const float*)&v1)[j]) << 16);
      s32k[k >> 1][n4 + j] = pk;
    }
  }
  __syncthreads();
  #pragma unroll
  for (int c = 0; c < 2; c++) {
    int id = tid + c * 256;
    int n = id >> 3, kc = id & 7;
    uint4 o;
    o.x = s32k[kc * 4 + 0][n];
    o.y = s32k[kc * 4 + 1][n];
    o.z = s32k[kc * 4 + 2][n];
    o.w = s32k[kc * 4 + 3][n];
    *(uint4*)(de + (size_t)n * Ksub + kc * 8) = o;
  }
}

// ---------------- gating (+ fused x->bf16 convert): 1 wave per token ----------------
__global__ void gating_kernel(const float* __restrict__ x,
                              const float* __restrict__ Wg,
                              const float* __restrict__ bg,
                              float* __restrict__ gate_out,
                              unsigned short* __restrict__ xb,
                              int* __restrict__ cnt,
                              int* __restrict__ tokIdx,
                              float* __restrict__ tokW, int T) {
  int wv = threadIdx.x >> 6, lane = threadIdx.x & 63;
  int t = blockIdx.x * 4 + wv;
  if (t >= T) return;
  const float* xr = x + (size_t)t * D_MODEL + lane * 16;
  float acc[N_EXP];
  #pragma unroll
  for (int e = 0; e < N_EXP; e++) acc[e] = 0.f;
  ushort4 xc[4];
  #pragma unroll
  for (int q = 0; q < 4; q++) {
    float4 xv = *(const float4*)(xr + q * 4);
    xc[q].x = f2bf(xv.x); xc[q].y = f2bf(xv.y);
    xc[q].z = f2bf(xv.z); xc[q].w = f2bf(xv.w);
    #pragma unroll
    for (int r = 0; r < 4; r++) {
      float xs = ((const float*)&xv)[r];
      const float* wrow = Wg + (size_t)(lane * 16 + q * 4 + r) * N_EXP;
      float4 wa = *(const float4*)wrow;
      float4 wb = *(const float4*)(wrow + 4);
      acc[0] += xs * wa.x; acc[1] += xs * wa.y; acc[2] += xs * wa.z; acc[3] += xs * wa.w;
      acc[4] += xs * wb.x; acc[5] += xs * wb.y; acc[6] += xs * wb.z; acc[7] += xs * wb.w;
    }
  }
  unsigned short* xbr = xb + (size_t)t * D_MODEL + lane * 16;
  #pragma unroll
  for (int q = 0; q < 4; q++) *(ushort4*)(xbr + q * 4) = xc[q];
  #pragma unroll
  for (int off = 32; off > 0; off >>= 1) {
    #pragma unroll
    for (int e = 0; e < N_EXP; e++) acc[e] += __shfl_xor(acc[e], off);
  }
  if (lane == 0) {
    float l[N_EXP], p[N_EXP];
    float m = -1e30f;
    #pragma unroll
    for (int e = 0; e < N_EXP; e++) { l[e] = acc[e] + bg[e]; m = fmaxf(m, l[e]); }
    float s = 0.f;
    #pragma unroll
    for (int e = 0; e < N_EXP; e++) { p[e] = __expf(l[e] - m); s += p[e]; }
    float inv = 1.f / s;
    #pragma unroll
    for (int e = 0; e < N_EXP; e++) { p[e] *= inv; gate_out[(size_t)t * N_EXP + e] = p[e]; }
    int e1 = 0;
    #pragma unroll
    for (int e = 1; e < N_EXP; e++) if (p[e] > p[e1]) e1 = e;
    int e2 = (e1 == 0) ? 1 : 0;
    #pragma unroll
    for (int e = 0; e < N_EXP; e++) if (e != e1 && p[e] > p[e2]) e2 = e;
    int pos = atomicAdd(cnt + e1, 1);
    tokIdx[(size_t)e1 * T + pos] = t; tokW[(size_t)e1 * T + pos] = p[e1];
    pos = atomicAdd(cnt + e2, 1);
    tokIdx[(size_t)e2 * T + pos] = t; tokW[(size_t)e2 * T + pos] = p[e2];
  }
}

// ---------------- schedule: build row-tile table ----------------
__global__ void schedule_kernel(const int* __restrict__ cnt, int* __restrict__ meta,
                                int* __restrict__ tE, int* __restrict__ tB,
                                int* __restrict__ tV, int T, int maxTiles) {
  if (threadIdx.x != 0 || blockIdx.x != 0) return;
  int t = 0;
  for (int e = 0; e < N_EXP; e++) {
    int c = cnt[e];
    for (int r = 0; r < c && t < maxTiles; r += BM) {
      tE[t] = e; tB[t] = e * T + r; tV[t] = min(BM, c - r); t++;
    }
  }
  meta[0] = t;
}

// ======== pipelined BK=32 K-loop machinery ========
// Buffer b (ushort idx, base b*8192): A rows [0,4096), B rows [4096,8192).
// Row = 32 ushorts (64B, 4 chunks of 16B). LDS chunk c holds global chunk
// (c-(r>>1))&3; read at c_eff=(l4+(r>>1))&3 -> global chunk l4. 2-way banks.
#define STAGE(b, kt) { _Pragma("unroll") for (int p_ = 0; p_ < 2; p_++) { \
    gl_lds16(srcA[p_] + (size_t)(kt) * BK, &LDSU[(b) * 8192 + (w * 32 + p_ * 16) * 32]); \
    gl_lds16(srcB[p_] + (size_t)(kt) * BK, &LDSU[(b) * 8192 + 4096 + (w * 32 + p_ * 16) * 32]); } }

#define COMPUTE(b) { \
    bf16x8 ra[4], rb[4]; \
    _Pragma("unroll") for (int m_ = 0; m_ < 4; m_++) { \
      int row_ = wr * 64 + m_ * 16 + l15; \
      ra[m_] = *(const bf16x8*)&LDSU[(b) * 8192 + row_ * 32 + (((l4 + (row_ >> 1)) & 3) << 3)]; } \
    _Pragma("unroll") for (int n_ = 0; n_ < 4; n_++) { \
      int rb_ = wc * 64 + n_ * 16 + l15; \
      rb[n_] = *(const bf16x8*)&LDSU[(b) * 8192 + 4096 + rb_ * 32 + (((l4 + (rb_ >> 1)) & 3) << 3)]; } \
    _Pragma("unroll") for (int m_ = 0; m_ < 4; m_++) \
      _Pragma("unroll") for (int n_ = 0; n_ < 4; n_++) \
        acc[m_][n_] = __builtin_amdgcn_mfma_f32_16x16x32_bf16(ra[m_], rb[n_], acc[m_][n_], 0, 0, 0); }

#define BAR() { __builtin_amdgcn_s_barrier(); asm volatile("" ::: "memory"); }
#define WAITVM(N) asm volatile("s_waitcnt vmcnt(" #N ")" ::: "memory");

// 3-buffer, depth-2. NT must satisfy (NT-2) % 3 == 0 (holds for 32).
#define PIPE3(NT) \
  STAGE(0, 0); STAGE(1, 1); \
  for (int it = 0; it < ((NT) - 2) / 3; it++) { \
    int kt = 3 * it; \
    STAGE(2, kt + 2); WAITVM(8); BAR(); COMPUTE(0); BAR(); \
    STAGE(0, kt + 3); WAITVM(8); BAR(); COMPUTE(1); BAR(); \
    STAGE(1, kt + 4); WAITVM(8); BAR(); COMPUTE(2); BAR(); \
  } \
  WAITVM(4); BAR(); COMPUTE(0); BAR(); \
  WAITVM(0); BAR(); COMPUTE(1);

// 4-buffer, depth-3 (buffer = kt & 3; unroll makes indices literal).
#define PIPE4(NT) \
  STAGE(0, 0); STAGE(1, 1); STAGE(2, 2); \
  _Pragma("unroll 4") \
  for (int kt = 0; kt < (NT) - 3; kt++) { \
    STAGE((kt + 3) & 3, kt + 3); \
    WAITVM(12); BAR(); COMPUTE(kt & 3); BAR(); \
  } \
  WAITVM(8); BAR(); COMPUTE(((NT) - 3) & 3); BAR(); \
  WAITVM(4); BAR(); COMPUTE(((NT) - 2) & 3); BAR(); \
  WAITVM(0); BAR(); COMPUTE(((NT) - 1) & 3);

// ---------------- GEMM1: h = relu(x_bf16 @ W1 + b1)  (cb-major works, 3-buf) ----------------
__global__ __launch_bounds__(256)
void gemm1_kernel(const unsigned short* __restrict__ xb,
                  const unsigned short* __restrict__ w1t,  // [e][D_FF][D_MODEL] bf16
                  const float* __restrict__ b1,
                  const int* __restrict__ meta,
                  const int* __restrict__ tE, const int* __restrict__ tB,
                  const int* __restrict__ tV, const int* __restrict__ tokIdx,
                  unsigned short* __restrict__ h, int nT) {
  __shared__ unsigned short LDSU[24576];  // 48 KiB = 3 buffers

  int total = gridDim.x;
  int L = blockIdx.x;
  int q = total >> 3, r8 = total & 7;
  int xcd = L & 7, idx = L >> 3;
  int work = (xcd < r8) ? (xcd * (q + 1) + idx) : (r8 * (q + 1) + (xcd - r8) * q + idx);
  // cb-major: within an XCD chunk, consecutive works share the B panel (L2-resident)
  int cb = work / nT;
  int tile = work - cb * nT;
  if (tile >= meta[0]) return;
  int e = tE[tile], base = tB[tile], valid = tV[tile];
  int tid = threadIdx.x;

  int w = tid >> 6, lane = tid & 63;
  int wr = w >> 1, wc = w & 1;
  int l15 = lane & 15, l4 = lane >> 4;
  int lrow = lane >> 2, lch = lane & 3;

  const unsigned short* panel = w1t + (size_t)e * D_FF * D_MODEL;
  const unsigned short* srcA[2];
  const unsigned short* srcB[2];
  #pragma unroll
  for (int p = 0; p < 2; p++) {
    int r = w * 32 + p * 16 + lrow;
    int tok = tokIdx[base + (r < valid ? r : valid - 1)];
    int g = (lch - (r >> 1)) & 3;
    srcA[p] = xb + (size_t)tok * D_MODEL + g * 8;
    srcB[p] = panel + (size_t)(cb * BN + r) * D_MODEL + g * 8;
  }

  f32x4 acc[4][4];
  #pragma unroll
  for (int m = 0; m < 4; m++)
    #pragma unroll
    for (int n = 0; n < 4; n++) acc[m][n] = (f32x4){0.f, 0.f, 0.f, 0.f};

  PIPE3(D_MODEL / BK);  // 32

  #pragma unroll
  for (int n = 0; n < 4; n++) {
    int colc = cb * BN + wc * 64 + n * 16 + l15;
    float bias = b1[(size_t)e * D_FF + colc];
    #pragma unroll
    for (int m = 0; m < 4; m++) {
      #pragma unroll
      for (int r = 0; r < 4; r++) {
        int row = wr * 64 + m * 16 + l4 * 4 + r;
        float v = acc[m][n][r] + bias;
        v = v > 0.f ? v : 0.f;
        h[(size_t)(tile * BM + row) * D_FF + colc] = f2bf(v);
      }
    }
  }
}

// ---------------- GEMM2: out += w * (h @ W2 + b2)  (tile-major works, 4-buf depth-3) ----------------
__global__ __launch_bounds__(256)
void gemm2_kernel(const unsigned short* __restrict__ h,
                  const unsigned short* __restrict__ w2t,  // [e][D_MODEL][D_FF] bf16
                  const float* __restrict__ b2,
                  const int* __restrict__ meta,
                  const int* __restrict__ tE, const int* __restrict__ tB,
                  const int* __restrict__ tV, const int* __restrict__ tokIdx,
                  const float* __restrict__ tokW,
                  float* __restrict__ out) {
  __shared__ unsigned short LDSU[32768];  // 64 KiB = 4 buffers

  int total = gridDim.x;
  int L = blockIdx.x;
  int q = total >> 3, r8 = total & 7;
  int xcd = L & 7, idx = L >> 3;
  int work = (xcd < r8) ? (xcd * (q + 1) + idx) : (r8 * (q + 1) + (xcd - r8) * q + idx);
  int tile = work >> 3;          // ncol = D_MODEL/BN = 8
  int cb = work & 7;
  if (tile >= meta[0]) return;
  int e = tE[tile], base = tB[tile], valid = tV[tile];
  int tid = threadIdx.x;

  int w = tid >> 6, lane = tid & 63;
  int wr = w >> 1, wc = w & 1;
  int l15 = lane & 15, l4 = lane >> 4;
  int lrow = lane >> 2, lch = lane & 3;

  const unsigned short* panel = w2t + (size_t)e * D_MODEL * D_FF;
  const unsigned short* srcA[2];
  const unsigned short* srcB[2];
  #pragma unroll
  for (int p = 0; p < 2; p++) {
    int r = w * 32 + p * 16 + lrow;
    int g = (lch - (r >> 1)) & 3;
    srcA[p] = h + (size_t)(tile * BM + r) * D_FF + g * 8;
    srcB[p] = panel + (size_t)(cb * BN + r) * D_FF + g * 8;
  }

  f32x4 acc[4][4];
  #pragma unroll
  for (int m = 0; m < 4; m++)
    #pragma unroll
    for (int n = 0; n < 4; n++) acc[m][n] = (f32x4){0.f, 0.f, 0.f, 0.f};

  PIPE4(D_FF / BK);  // 128

  float biasv[4];
  #pragma unroll
  for (int n = 0; n < 4; n++)
    biasv[n] = b2[(size_t)e * D_MODEL + cb * BN + wc * 64 + n * 16 + l15];

  #pragma unroll
  for (int m = 0; m < 4; m++) {
    #pragma unroll
    for (int r = 0; r < 4; r++) {
      int row = wr * 64 + m * 16 + l4 * 4 + r;
      if (row < valid) {
        int tok = tokIdx[base + row];
        float wgt = tokW[base + row];
        float* orow = out + (size_t)tok * D_MODEL + cb * BN + wc * 64 + l15;
        #pragma unroll
        for (int n = 0; n < 4; n++)
          atomicAdd(orow + n * 16, (acc[m][n][r] + biasv[n]) * wgt);
      }
    }
  }
}

// ---------------- host ----------------
extern "C" void kernel_launch(void* const* d_in, const int* in_sizes, int n_in,
                              void* d_out, int out_size, void* d_ws, size_t ws_size,
                              hipStream_t stream) {
  const float* x  = (const float*)d_in[0];
  const float* W1 = (const float*)d_in[1];
  const float* b1 = (const float*)d_in[2];
  const float* W2 = (const float*)d_in[3];
  const float* b2 = (const float*)d_in[4];
  const float* Wg = (const float*)d_in[5];
  const float* bg = (const float*)d_in[6];

  int T = in_sizes[0] / D_MODEL;  // 8192
  float* out = (float*)d_out;
  float* gate_out = out + (size_t)T * D_MODEL;

  char* ws = (char*)d_ws;
  int* cnt  = (int*)(ws + 0);
  int* meta = (int*)(ws + 64);
  int* tE   = (int*)(ws + 128);
  int* tB   = (int*)(ws + 1024);
  int* tV   = (int*)(ws + 2048);
  size_t off = 4096;
  int* tokIdx = (int*)(ws + off);   off += (size_t)N_EXP * T * 4;
  float* tokW = (float*)(ws + off); off += (size_t)N_EXP * T * 4;
  unsigned short* xb = (unsigned short*)(ws + off); off += (size_t)T * D_MODEL * 2;
  off = (off + 255) & ~(size_t)255;

  int maxTiles = (2 * T) / BM + N_EXP;  // 136

  unsigned short* w1t = (unsigned short*)(ws + off); off += (size_t)N_EXP * D_MODEL * D_FF * 2;
  unsigned short* w2t = (unsigned short*)(ws + off); off += (size_t)N_EXP * D_MODEL * D_FF * 2;
  unsigned short* h   = (unsigned short*)(ws + off);

  hipMemsetAsync(d_out, 0, (size_t)T * D_MODEL * sizeof(float), stream);
  hipMemsetAsync(cnt, 0, N_EXP * sizeof(int), stream);

  gating_kernel<<<(T + 3) / 4, 256, 0, stream>>>(x, Wg, bg, gate_out, xb, cnt, tokIdx, tokW, T);
  schedule_kernel<<<1, 64, 0, stream>>>(cnt, meta, tE, tB, tV, T, maxTiles);

  transpose_convert_kernel<<<dim3(D_MODEL / 64, D_FF / 64, N_EXP), 256, 0, stream>>>(
      W1, w1t, D_MODEL, D_FF, (unsigned long long)D_MODEL * D_FF);
  transpose_convert_kernel<<<dim3(D_FF / 64, D_MODEL / 64, N_EXP), 256, 0, stream>>>(
      W2, w2t, D_FF, D_MODEL, (unsigned long long)D_FF * D_MODEL);

  gemm1_kernel<<<maxTiles * (D_FF / BN), 256, 0, stream>>>(
      xb, w1t, b1, meta, tE, tB, tV, tokIdx, h, maxTiles);
  gemm2_kernel<<<maxTiles * (D_MODEL / BN), 256, 0, stream>>>(
      h, w2t, b2, meta, tE, tB, tV, tokIdx, tokW, out);
}